// Round 11
// baseline (249.448 us; speedup 1.0000x reference)
//
#include <hip/hip_runtime.h>

// Problem constants
#define B_    4
#define A_    66000
#define NA_   (B_ * A_)          // 264000 anchors
#define N_    30
#define T_    5
#define NLT   5
#define CSUM  277
#define CTOT  278                // 1 + 277 logits per anchor
#define ROWS  31                 // N+1 table rows per batch
#define NROWS (B_ * ROWS)        // 124
#define WPR   11                 // odd row stride (>=10 so w1 read stays in-row)
#define NBW   (NROWS * WPR)      // 1364 words
#define NE    (NA_ * CTOT)       // 73,392,000 elements
#define NE8   (NE / 8)           // 9,174,000 8-packs (exact)

#define BLK       256
#define GRID_CLS  2048
#define GRID_PREP 512

typedef float fx4 __attribute__((ext_vector_type(4)));
typedef float fx2 __attribute__((ext_vector_type(2)));

// ---------------- helpers ----------------

// Pair focal as float2 math (invites v_pk_*_f32).
// b2 = 2 label bits; c25/c75 = mask*0.25 / mask*0.75 for this pair.
__device__ __forceinline__ fx2 pair_focal(float x0, float x1, unsigned b2,
                                          float c25, float c75, fx2 acc) {
    bool y0 = (b2 & 1u) != 0u, y1 = (b2 & 2u) != 0u;
    float s0 = y0 ? -x0 : x0,  s1 = y1 ? -x1 : x1;
    float k0 = y0 ? c25 : c75, k1 = y1 ? c25 : c75;
    // t = exp(-|s|) = exp2(-|x|*log2e)   (|s| == |x|)
    float t0 = __builtin_amdgcn_exp2f(-fabsf(x0) * 1.4426950408889634f);
    float t1 = __builtin_amdgcn_exp2f(-fabsf(x1) * 1.4426950408889634f);
    fx2 t = {t0, t1};
    fx2 u = t + 1.0f;
    fx2 L = { __builtin_amdgcn_logf(u.x), __builtin_amdgcn_logf(u.y) }; // log2(1+t)
    fx2 sp = { fmaxf(s0, 0.f), fmaxf(s1, 0.f) };
    sp += L * 0.6931471805599453f;                 // softplus(s)
    fx2 inv = { __builtin_amdgcn_rcpf(u.x), __builtin_amdgcn_rcpf(u.y) };
    fx2 ti = t * inv;
    fx2 sig = { s0 >= 0.f ? inv.x : ti.x, s1 >= 0.f ? inv.y : ti.y };   // sigmoid(s)
    fx2 term = { k0, k1 };
    term *= sp;
    return acc + term * (sig * sig);
}

__device__ __forceinline__ float sl1(float d) {
    float ad = fabsf(d);
    return (ad < (1.f / 9.f)) ? 4.5f * ad * ad : ad - (1.f / 18.f);
}

__device__ __forceinline__ float block_reduce(float v, float* sdata) {
    #pragma unroll
    for (int off = 32; off > 0; off >>= 1) v += __shfl_down(v, off, 64);
    int lane = threadIdx.x & 63, wid = threadIdx.x >> 6;
    if (lane == 0) sdata[wid] = v;
    __syncthreads();
    int nw = blockDim.x >> 6;
    if (wid == 0) {
        v = (lane < nw) ? sdata[lane] : 0.f;
        #pragma unroll
        for (int off = 32; off > 0; off >>= 1) v += __shfl_down(v, off, 64);
    }
    return v;
}

// ---------------- kernels ----------------

// Fused prep: block 0 builds the bit-packed label table + resets the
// completion counter; all blocks do regression loss + pos count + rowid.
__global__ __launch_bounds__(BLK) void prep_kernel(
    const int* __restrict__ gtl, const int* __restrict__ lbin,
    const float* __restrict__ pred, const float* __restrict__ gt,
    unsigned* __restrict__ bits, int* __restrict__ rowid,
    float* __restrict__ reg_part, float* __restrict__ pos_part,
    unsigned* __restrict__ cnt)
{
    if (blockIdx.x == 0) {
        for (int i = threadIdx.x; i < NBW; i += BLK) bits[i] = 0u;
        __syncthreads();
        int tid = threadIdx.x;
        if (tid < NROWS && (tid % ROWS) > 0) atomicOr(&bits[tid * WPR], 1u); // pos bit
        for (int idx = tid; idx < B_ * N_ * NLT; idx += BLK) {
            int lt = idx % NLT;
            int bn = idx / NLT;
            int n  = bn % N_;
            int b  = bn / N_;
            const int nc_arr[NLT]  = {10, 23, 69, 163, 12};
            const int off_arr[NLT] = {0, 10, 33, 102, 265};
            int nc  = nc_arr[lt];
            int off = off_arr[lt] + 1;          // +1: col 0 is pos
            const int* g = gtl + (size_t)(((b * N_ + n) * NLT + lt)) * T_;
            int row = b * ROWS + (n + 1);
            bool valid = true;
            #pragma unroll
            for (int t = 0; t < T_; ++t) {
                int v = g[t];
                valid = valid && (v >= 0);
                if (valid) {
                    int c = off + ((v < nc) ? v : (nc - 1));
                    atomicOr(&bits[row * WPR + (c >> 5)], 1u << (c & 31));
                }
            }
        }
        if (tid == 0) {
            rowid[NA_] = 0;     // sentinel for the unconditional rowid[a+1] load
            cnt[0] = 0u;        // reset last-block counter each call (replay-safe)
        }
    }

    float racc = 0.f, pacc = 0.f;
    unsigned stride = gridDim.x * BLK;
    for (unsigned i = blockIdx.x * BLK + threadIdx.x; i < NA_; i += stride) {
        int lb = lbin[i];
        unsigned b = i / A_;
        rowid[i] = (lb < 0) ? -1 : (int)((b * ROWS + (unsigned)(lb > 0 ? lb : 0)) * WPR);
        if (lb > 0) {
            pacc += 1.f;
            float4 pv = *(const float4*)(pred + (size_t)4 * i);
            float4 gv = *(const float4*)(gt + (size_t)4 * i);
            racc += sl1(pv.x - gv.x) + sl1(pv.y - gv.y) + sl1(pv.z - gv.z) + sl1(pv.w - gv.w);
        }
    }
    __shared__ float sdata[BLK / 64];
    float r = block_reduce(racc, sdata);
    __syncthreads();
    float p = block_reduce(pacc, sdata);
    if (threadIdx.x == 0) {
        reg_part[blockIdx.x] = r;
        pos_part[blockIdx.x] = p;
    }
}

// Main classification focal-loss sum: 32 B (8 elements) per lane-iteration
// (proven sweet spot: 2 lanes per 64B line, immediate reuse; 64 B/lane
// thrashes L1 across interleaved waves -> 4.5x slowdown, R10).
// Branch-free boundary handling. Last block folds in the final reduction.
__global__ __launch_bounds__(BLK) void cls_kernel(
    const fx4* __restrict__ conf4, const int* __restrict__ rowid,
    const unsigned* __restrict__ bits, float* __restrict__ partials,
    const float* __restrict__ reg_part, const float* __restrict__ pos_part,
    unsigned* __restrict__ cnt, float* __restrict__ out)
{
    __shared__ unsigned lbits[NBW];
    for (int i = threadIdx.x; i < NBW; i += BLK) lbits[i] = bits[i];
    __syncthreads();

    fx2 acc2 = {0.f, 0.f};
    unsigned stride = gridDim.x * BLK;
    for (unsigned i = blockIdx.x * BLK + threadIdx.x; i < NE8; i += stride) {
        fx4 x0 = conf4[2u * i];          // elements 8i..8i+3
        fx4 x1 = conf4[2u * i + 1u];     // elements 8i+4..8i+7
        unsigned i8 = i * 8u;
        unsigned a  = i8 / CTOT;         // magic-mul div
        unsigned c0 = i8 - a * CTOT;     // even, 0..276
        int ridA = rowid[a];
        int ridB = rowid[a + 1u];        // sentinel makes this always safe
        unsigned bwA = (ridA >= 0) ? (unsigned)ridA : 0u;
        unsigned bwB = (ridB >= 0) ? (unsigned)ridB : 0u;
        float mA = (ridA >= 0) ? 1.f : 0.f;
        float mB = (ridB >= 0) ? 1.f : 0.f;
        unsigned wi = c0 >> 5, sh = c0 & 31u;     // wi <= 8
        unsigned w0  = lbits[bwA + wi];
        unsigned w1  = lbits[bwA + wi + 1u];      // WPR=11 keeps this in-row
        unsigned wB0 = lbits[bwB];
        // 8-bit window of row-A labels at c0 (sh+7 <= 38 < 64: always covered)
        unsigned wfull = (unsigned)((((unsigned long long)w1 << 32) | w0) >> sh);
        unsigned bnd  = CTOT - c0;                // elements k < bnd belong to A
        bool cross    = bnd < 8u;                 // c0 in {272,274,276}
        unsigned bndc = cross ? bnd : 8u;
        unsigned w8   = cross ? ((wfull & ((1u << bndc) - 1u)) | (wB0 << bndc))
                              : wfull;
        // bnd is even -> pairs never straddle the boundary
        float m1 = (cross && bnd <= 2u) ? mB : mA;   // elems 2,3
        float m2 = (cross && bnd <= 4u) ? mB : mA;   // elems 4,5
        float m3 = cross               ? mB : mA;    // elems 6,7 (bnd<=6 always)
        acc2 = pair_focal(x0.x, x0.y,  w8 & 3u,       0.25f * mA, 0.75f * mA, acc2);
        acc2 = pair_focal(x0.z, x0.w, (w8 >> 2) & 3u, 0.25f * m1, 0.75f * m1, acc2);
        acc2 = pair_focal(x1.x, x1.y, (w8 >> 4) & 3u, 0.25f * m2, 0.75f * m2, acc2);
        acc2 = pair_focal(x1.z, x1.w, (w8 >> 6) & 3u, 0.25f * m3, 0.75f * m3, acc2);
    }

    __shared__ float sdata[BLK / 64];
    float r = block_reduce(acc2.x + acc2.y, sdata);
    __shared__ bool sdone;
    if (threadIdx.x == 0) {
        partials[blockIdx.x] = r;
        __threadfence();   // release: partial visible agent-wide before counter
        unsigned prev = __hip_atomic_fetch_add(cnt, 1u, __ATOMIC_ACQ_REL,
                                               __HIP_MEMORY_SCOPE_AGENT);
        sdone = (prev == (unsigned)(GRID_CLS - 1));
    }
    __syncthreads();

    if (sdone) {
        // last block: reduce all partials with agent-scope (coherent) loads
        float c = 0.f, rg = 0.f, pz = 0.f;
        for (int i = threadIdx.x; i < GRID_CLS; i += BLK)
            c += __hip_atomic_load(&partials[i], __ATOMIC_RELAXED,
                                   __HIP_MEMORY_SCOPE_AGENT);
        for (int i = threadIdx.x; i < GRID_PREP; i += BLK) {
            rg += __hip_atomic_load(&reg_part[i], __ATOMIC_RELAXED,
                                    __HIP_MEMORY_SCOPE_AGENT);
            pz += __hip_atomic_load(&pos_part[i], __ATOMIC_RELAXED,
                                    __HIP_MEMORY_SCOPE_AGENT);
        }
        __syncthreads();           // sdata reuse
        c = block_reduce(c, sdata);
        __syncthreads();
        rg = block_reduce(rg, sdata);
        __syncthreads();
        pz = block_reduce(pz, sdata);
        if (threadIdx.x == 0) {
            float np = fmaxf(1.f, pz);
            out[0] = rg / (np * 4.f);   // regression_loss
            out[1] = c / np;            // cls_loss
        }
    }
}

// ---------------- launch ----------------

extern "C" void kernel_launch(void* const* d_in, const int* in_sizes, int n_in,
                              void* d_out, int out_size, void* d_ws, size_t ws_size,
                              hipStream_t stream) {
    const float* conf = (const float*)d_in[0];
    const float* pred = (const float*)d_in[1];
    const float* gt   = (const float*)d_in[2];
    const int*   gtl  = (const int*)d_in[3];
    const int*   lbin = (const int*)d_in[4];
    float* out = (float*)d_out;

    unsigned* bits  = (unsigned*)d_ws;
    int* rowid      = (int*)(bits + NBW);          // NA_+1 entries (sentinel)
    float* cls_part = (float*)(rowid + NA_ + 1);
    float* reg_part = cls_part + GRID_CLS;
    float* pos_part = reg_part + GRID_PREP;
    unsigned* cnt   = (unsigned*)(pos_part + GRID_PREP);

    hipLaunchKernelGGL(prep_kernel, dim3(GRID_PREP), dim3(BLK), 0, stream,
                       gtl, lbin, pred, gt, bits, rowid, reg_part, pos_part, cnt);
    hipLaunchKernelGGL(cls_kernel, dim3(GRID_CLS), dim3(BLK), 0, stream,
                       (const fx4*)conf, rowid, bits, cls_part,
                       reg_part, pos_part, cnt, out);
}

// Round 12
// 73.202 us; speedup vs baseline: 3.4077x; 3.4077x over previous
//
#include <hip/hip_runtime.h>

// Problem constants
#define B_    4
#define A_    66000
#define NA_   (B_ * A_)          // 264000 anchors
#define N_    30
#define T_    5
#define NLT   5
#define CSUM  277
#define CTOT  278                // 1 + 277 logits per anchor
#define ROWS  31                 // N+1 table rows per batch
#define NROWS (B_ * ROWS)        // 124
#define WPR   11                 // odd row stride (>=10 so w1 read stays in-row)
#define NBW   (NROWS * WPR)      // 1364 words
#define NE    (NA_ * CTOT)       // 73,392,000 elements
#define NE16  (NE / 16)          // 4,587,000 16-packs (exact)

#define BLK       256
#define GRID_CLS  2048
#define GRID_PREP 512

typedef float fx4 __attribute__((ext_vector_type(4)));
typedef float fx2 __attribute__((ext_vector_type(2)));

// ---------------- helpers ----------------

// Pair focal as float2 math (invites v_pk_*_f32).
// b2 = 2 label bits; c25/c75 = mask*0.25 / mask*0.75 for this pair.
__device__ __forceinline__ fx2 pair_focal(float x0, float x1, unsigned b2,
                                          float c25, float c75, fx2 acc) {
    bool y0 = (b2 & 1u) != 0u, y1 = (b2 & 2u) != 0u;
    float s0 = y0 ? -x0 : x0,  s1 = y1 ? -x1 : x1;
    float k0 = y0 ? c25 : c75, k1 = y1 ? c25 : c75;
    // t = exp(-|s|) = exp2(-|x|*log2e)   (|s| == |x|)
    float t0 = __builtin_amdgcn_exp2f(-fabsf(x0) * 1.4426950408889634f);
    float t1 = __builtin_amdgcn_exp2f(-fabsf(x1) * 1.4426950408889634f);
    fx2 t = {t0, t1};
    fx2 u = t + 1.0f;
    fx2 L = { __builtin_amdgcn_logf(u.x), __builtin_amdgcn_logf(u.y) }; // log2(1+t)
    fx2 sp = { fmaxf(s0, 0.f), fmaxf(s1, 0.f) };
    sp += L * 0.6931471805599453f;                 // softplus(s)
    fx2 inv = { __builtin_amdgcn_rcpf(u.x), __builtin_amdgcn_rcpf(u.y) };
    fx2 ti = t * inv;
    fx2 sig = { s0 >= 0.f ? inv.x : ti.x, s1 >= 0.f ? inv.y : ti.y };   // sigmoid(s)
    fx2 term = { k0, k1 };
    term *= sp;
    return acc + term * (sig * sig);
}

__device__ __forceinline__ float sl1(float d) {
    float ad = fabsf(d);
    return (ad < (1.f / 9.f)) ? 4.5f * ad * ad : ad - (1.f / 18.f);
}

__device__ __forceinline__ float block_reduce(float v, float* sdata) {
    #pragma unroll
    for (int off = 32; off > 0; off >>= 1) v += __shfl_down(v, off, 64);
    int lane = threadIdx.x & 63, wid = threadIdx.x >> 6;
    if (lane == 0) sdata[wid] = v;
    __syncthreads();
    int nw = blockDim.x >> 6;
    if (wid == 0) {
        v = (lane < nw) ? sdata[lane] : 0.f;
        #pragma unroll
        for (int off = 32; off > 0; off >>= 1) v += __shfl_down(v, off, 64);
    }
    return v;
}

// ---------------- kernels ----------------

// Fused prep: block 0 builds the bit-packed label table; all blocks do the
// regression loss + pos count + per-anchor rowid.
// NOTE: no agent-scope fences/atomics anywhere. On 8-XCD CDNA4 a per-block
// __threadfence + device atomic forces per-XCD L2 writeback/invalidate and a
// serialized far-atomic -> ~220us tail (R10/R11 disaster). Separate tiny
// finalize kernel is stream-ordered and effectively free.
__global__ __launch_bounds__(BLK) void prep_kernel(
    const int* __restrict__ gtl, const int* __restrict__ lbin,
    const float* __restrict__ pred, const float* __restrict__ gt,
    unsigned* __restrict__ bits, int* __restrict__ rowid,
    float* __restrict__ reg_part, float* __restrict__ pos_part)
{
    if (blockIdx.x == 0) {
        for (int i = threadIdx.x; i < NBW; i += BLK) bits[i] = 0u;
        __syncthreads();
        int tid = threadIdx.x;
        if (tid < NROWS && (tid % ROWS) > 0) atomicOr(&bits[tid * WPR], 1u); // pos bit
        for (int idx = tid; idx < B_ * N_ * NLT; idx += BLK) {
            int lt = idx % NLT;
            int bn = idx / NLT;
            int n  = bn % N_;
            int b  = bn / N_;
            const int nc_arr[NLT]  = {10, 23, 69, 163, 12};
            const int off_arr[NLT] = {0, 10, 33, 102, 265};
            int nc  = nc_arr[lt];
            int off = off_arr[lt] + 1;          // +1: col 0 is pos
            const int* g = gtl + (size_t)(((b * N_ + n) * NLT + lt)) * T_;
            int row = b * ROWS + (n + 1);
            bool valid = true;
            #pragma unroll
            for (int t = 0; t < T_; ++t) {
                int v = g[t];
                valid = valid && (v >= 0);
                if (valid) {
                    int c = off + ((v < nc) ? v : (nc - 1));
                    atomicOr(&bits[row * WPR + (c >> 5)], 1u << (c & 31));
                }
            }
        }
        if (tid == 0) rowid[NA_] = 0;   // sentinel for unconditional rowid[a+1]
    }

    float racc = 0.f, pacc = 0.f;
    unsigned stride = gridDim.x * BLK;
    for (unsigned i = blockIdx.x * BLK + threadIdx.x; i < NA_; i += stride) {
        int lb = lbin[i];
        unsigned b = i / A_;
        rowid[i] = (lb < 0) ? -1 : (int)((b * ROWS + (unsigned)(lb > 0 ? lb : 0)) * WPR);
        if (lb > 0) {
            pacc += 1.f;
            float4 pv = *(const float4*)(pred + (size_t)4 * i);
            float4 gv = *(const float4*)(gt + (size_t)4 * i);
            racc += sl1(pv.x - gv.x) + sl1(pv.y - gv.y) + sl1(pv.z - gv.z) + sl1(pv.w - gv.w);
        }
    }
    __shared__ float sdata[BLK / 64];
    float r = block_reduce(racc, sdata);
    __syncthreads();
    float p = block_reduce(pacc, sdata);
    if (threadIdx.x == 0) {
        reg_part[blockIdx.x] = r;
        pos_part[blockIdx.x] = p;
    }
}

// Main classification focal-loss sum: 64 B (16 elements) per lane-iteration,
// branch-free boundary handling. Per 16 elements: 1 magic-div, 2 rowid loads,
// 3 LDS broadcasts, 1 window build. (16-pack beat 8-pack by ~6us once the
// R10/R11 fence tail was removed from the comparison.)
__global__ __launch_bounds__(BLK) void cls_kernel(
    const fx4* __restrict__ conf4, const int* __restrict__ rowid,
    const unsigned* __restrict__ bits, float* __restrict__ partials)
{
    __shared__ unsigned lbits[NBW];
    for (int i = threadIdx.x; i < NBW; i += BLK) lbits[i] = bits[i];
    __syncthreads();

    fx2 acc2 = {0.f, 0.f};
    unsigned stride = gridDim.x * BLK;
    for (unsigned i = blockIdx.x * BLK + threadIdx.x; i < NE16; i += stride) {
        fx4 x0 = conf4[4u * i];          // elements 16i..16i+3
        fx4 x1 = conf4[4u * i + 1u];
        fx4 x2 = conf4[4u * i + 2u];
        fx4 x3 = conf4[4u * i + 3u];
        unsigned i16 = i * 16u;
        unsigned a  = i16 / CTOT;        // magic-mul div
        unsigned c0 = i16 - a * CTOT;    // even, 0..276
        int ridA = rowid[a];
        int ridB = rowid[a + 1u];        // sentinel makes this always safe
        unsigned bwA = (ridA >= 0) ? (unsigned)ridA : 0u;
        unsigned bwB = (ridB >= 0) ? (unsigned)ridB : 0u;
        float mA = (ridA >= 0) ? 1.f : 0.f;
        float mB = (ridB >= 0) ? 1.f : 0.f;
        float c25A = 0.25f * mA, c75A = 0.75f * mA;
        float c25B = 0.25f * mB, c75B = 0.75f * mB;
        unsigned wi = c0 >> 5, sh = c0 & 31u;     // wi <= 8
        unsigned w0  = lbits[bwA + wi];
        unsigned w1  = lbits[bwA + wi + 1u];      // WPR=11 keeps this in-row
        unsigned wB0 = lbits[bwB];
        // 16-bit window of row-A labels at c0 (sh+15 <= 46 < 64: covered)
        unsigned wfull = (unsigned)((((unsigned long long)w1 << 32) | w0) >> sh);
        unsigned bnd  = CTOT - c0;                // elements k < bnd belong to A
        bool cross    = bnd < 16u;                // c0 >= 264; bnd in {2..14}, even
        unsigned w16  = cross ? ((wfull & ((1u << bnd) - 1u)) | (wB0 << bnd))
                              : wfull;
        // bnd even -> pairs never straddle; select coefs per pair
        #define PSEL(k) ((cross && bnd <= (2u*(k))) )
        float q25_1 = PSEL(1) ? c25B : c25A, q75_1 = PSEL(1) ? c75B : c75A;
        float q25_2 = PSEL(2) ? c25B : c25A, q75_2 = PSEL(2) ? c75B : c75A;
        float q25_3 = PSEL(3) ? c25B : c25A, q75_3 = PSEL(3) ? c75B : c75A;
        float q25_4 = PSEL(4) ? c25B : c25A, q75_4 = PSEL(4) ? c75B : c75A;
        float q25_5 = PSEL(5) ? c25B : c25A, q75_5 = PSEL(5) ? c75B : c75A;
        float q25_6 = PSEL(6) ? c25B : c25A, q75_6 = PSEL(6) ? c75B : c75A;
        float q25_7 = PSEL(7) ? c25B : c25A, q75_7 = PSEL(7) ? c75B : c75A;
        #undef PSEL
        acc2 = pair_focal(x0.x, x0.y,  w16 & 3u,        c25A, c75A, acc2);
        acc2 = pair_focal(x0.z, x0.w, (w16 >>  2) & 3u, q25_1, q75_1, acc2);
        acc2 = pair_focal(x1.x, x1.y, (w16 >>  4) & 3u, q25_2, q75_2, acc2);
        acc2 = pair_focal(x1.z, x1.w, (w16 >>  6) & 3u, q25_3, q75_3, acc2);
        acc2 = pair_focal(x2.x, x2.y, (w16 >>  8) & 3u, q25_4, q75_4, acc2);
        acc2 = pair_focal(x2.z, x2.w, (w16 >> 10) & 3u, q25_5, q75_5, acc2);
        acc2 = pair_focal(x3.x, x3.y, (w16 >> 12) & 3u, q25_6, q75_6, acc2);
        acc2 = pair_focal(x3.z, x3.w, (w16 >> 14) & 3u, q25_7, q75_7, acc2);
    }

    __shared__ float sdata[BLK / 64];
    float r = block_reduce(acc2.x + acc2.y, sdata);
    if (threadIdx.x == 0) partials[blockIdx.x] = r;
}

// Deterministic final reduction + normalization (separate tiny kernel:
// stream-ordered, no cross-block coherence games).
__global__ void finalize_kernel(
    const float* __restrict__ cls_part, const float* __restrict__ reg_part,
    const float* __restrict__ pos_part, float* __restrict__ out)
{
    __shared__ float sdata[256 / 64];
    float c = 0.f, r = 0.f, pz = 0.f;
    for (int i = threadIdx.x; i < GRID_CLS; i += blockDim.x) c += cls_part[i];
    for (int i = threadIdx.x; i < GRID_PREP; i += blockDim.x) {
        r  += reg_part[i];
        pz += pos_part[i];
    }
    c = block_reduce(c, sdata);
    __syncthreads();
    r = block_reduce(r, sdata);
    __syncthreads();
    pz = block_reduce(pz, sdata);
    if (threadIdx.x == 0) {
        float np = fmaxf(1.f, pz);
        out[0] = r / (np * 4.f);   // regression_loss
        out[1] = c / np;           // cls_loss
    }
}

// ---------------- launch ----------------

extern "C" void kernel_launch(void* const* d_in, const int* in_sizes, int n_in,
                              void* d_out, int out_size, void* d_ws, size_t ws_size,
                              hipStream_t stream) {
    const float* conf = (const float*)d_in[0];
    const float* pred = (const float*)d_in[1];
    const float* gt   = (const float*)d_in[2];
    const int*   gtl  = (const int*)d_in[3];
    const int*   lbin = (const int*)d_in[4];
    float* out = (float*)d_out;

    unsigned* bits  = (unsigned*)d_ws;
    int* rowid      = (int*)(bits + NBW);          // NA_+1 entries (sentinel)
    float* cls_part = (float*)(rowid + NA_ + 1);
    float* reg_part = cls_part + GRID_CLS;
    float* pos_part = reg_part + GRID_PREP;

    hipLaunchKernelGGL(prep_kernel, dim3(GRID_PREP), dim3(BLK), 0, stream,
                       gtl, lbin, pred, gt, bits, rowid, reg_part, pos_part);
    hipLaunchKernelGGL(cls_kernel, dim3(GRID_CLS), dim3(BLK), 0, stream,
                       (const fx4*)conf, rowid, bits, cls_part);
    hipLaunchKernelGGL(finalize_kernel, dim3(1), dim3(256), 0, stream,
                       cls_part, reg_part, pos_part, out);
}

// Round 13
// 67.264 us; speedup vs baseline: 3.7085x; 1.0883x over previous
//
#include <hip/hip_runtime.h>

// Problem constants
#define B_    4
#define A_    66000
#define NA_   (B_ * A_)          // 264000 anchors
#define N_    30
#define T_    5
#define NLT   5
#define CSUM  277
#define CTOT  278                // 1 + 277 logits per anchor
#define ROWS  31                 // N+1 table rows per batch
#define NROWS (B_ * ROWS)        // 124
#define WPR   11                 // odd row stride (>=10 so w1 read stays in-row)
#define NBW   (NROWS * WPR)      // 1364 words = 5456 B LDS
#define NE    (NA_ * CTOT)       // 73,392,000 elements
#define NE16  (NE / 16)          // 4,587,000 16-packs (exact)

#define BLK       256
#define GRID_CLS  2048           // 8 blocks/CU exactly on 256 CUs

typedef float fx4 __attribute__((ext_vector_type(4)));
typedef float fx2 __attribute__((ext_vector_type(2)));

// ---------------- helpers ----------------

// Pair focal as float2 math (invites v_pk_*_f32).
// b2 = 2 label bits; c25/c75 = mask*0.25 / mask*0.75 for this pair.
__device__ __forceinline__ fx2 pair_focal(float x0, float x1, unsigned b2,
                                          float c25, float c75, fx2 acc) {
    bool y0 = (b2 & 1u) != 0u, y1 = (b2 & 2u) != 0u;
    float s0 = y0 ? -x0 : x0,  s1 = y1 ? -x1 : x1;
    float k0 = y0 ? c25 : c75, k1 = y1 ? c25 : c75;
    // t = exp(-|s|) = exp2(-|x|*log2e)   (|s| == |x|)
    float t0 = __builtin_amdgcn_exp2f(-fabsf(x0) * 1.4426950408889634f);
    float t1 = __builtin_amdgcn_exp2f(-fabsf(x1) * 1.4426950408889634f);
    fx2 t = {t0, t1};
    fx2 u = t + 1.0f;
    fx2 L = { __builtin_amdgcn_logf(u.x), __builtin_amdgcn_logf(u.y) }; // log2(1+t)
    fx2 sp = { fmaxf(s0, 0.f), fmaxf(s1, 0.f) };
    sp += L * 0.6931471805599453f;                 // softplus(s)
    fx2 inv = { __builtin_amdgcn_rcpf(u.x), __builtin_amdgcn_rcpf(u.y) };
    fx2 ti = t * inv;
    fx2 sig = { s0 >= 0.f ? inv.x : ti.x, s1 >= 0.f ? inv.y : ti.y };   // sigmoid(s)
    fx2 term = { k0, k1 };
    term *= sp;
    return acc + term * (sig * sig);
}

__device__ __forceinline__ float sl1(float d) {
    float ad = fabsf(d);
    return (ad < (1.f / 9.f)) ? 4.5f * ad * ad : ad - (1.f / 18.f);
}

__device__ __forceinline__ float block_reduce(float v, float* sdata) {
    #pragma unroll
    for (int off = 32; off > 0; off >>= 1) v += __shfl_down(v, off, 64);
    int lane = threadIdx.x & 63, wid = threadIdx.x >> 6;
    if (lane == 0) sdata[wid] = v;
    __syncthreads();
    int nw = blockDim.x >> 6;
    if (wid == 0) {
        v = (lane < nw) ? sdata[lane] : 0.f;
        #pragma unroll
        for (int off = 32; off > 0; off >>= 1) v += __shfl_down(v, off, 64);
    }
    return v;
}

// ---------------- kernels ----------------

// Self-contained main kernel:
//  1) each block builds the bit-packed label table in its own LDS from gtl
//     (12 KB, L2-hot across blocks; LDS atomicOr, order-independent)
//  2) single-pass regression loss + pos count (grid > NA_, one anchor/thread)
//  3) 16-elements-per-lane focal sweep, rowid computed inline from lbin
// No prep kernel, no global bits/rowid arrays, no cross-block coherence games
// (R10/R11: per-block fence+agent-atomic on 8-XCD = ~220us serialized tail).
__global__ __launch_bounds__(BLK) void cls_kernel(
    const fx4* __restrict__ conf4, const int* __restrict__ lbin,
    const int* __restrict__ gtl,
    const float* __restrict__ pred, const float* __restrict__ gt,
    float* __restrict__ cls_part, float* __restrict__ reg_part,
    float* __restrict__ pos_part)
{
    __shared__ unsigned lbits[NBW];
    for (int i = threadIdx.x; i < NBW; i += BLK) lbits[i] = 0u;
    __syncthreads();
    // pos bit (col 0) for rows with dumy>0
    for (int r = threadIdx.x; r < NROWS; r += BLK)
        if ((r % ROWS) != 0) atomicOr(&lbits[r * WPR], 1u);
    // one-hot class bits (cols 1..277), cumprod-valid over T
    for (int idx = threadIdx.x; idx < B_ * N_ * NLT; idx += BLK) {
        int lt = idx % NLT;
        int bn = idx / NLT;
        int n  = bn % N_;
        int b  = bn / N_;
        const int nc_arr[NLT]  = {10, 23, 69, 163, 12};
        const int off_arr[NLT] = {0, 10, 33, 102, 265};
        int nc  = nc_arr[lt];
        int off = off_arr[lt] + 1;              // +1: col 0 is pos
        const int* g = gtl + (size_t)(((b * N_ + n) * NLT + lt)) * T_;
        int row = b * ROWS + (n + 1);
        bool valid = true;
        #pragma unroll
        for (int t = 0; t < T_; ++t) {
            int v = g[t];
            valid = valid && (v >= 0);
            if (valid) {
                int c = off + ((v < nc) ? v : (nc - 1));
                atomicOr(&lbits[row * WPR + (c >> 5)], 1u << (c & 31));
            }
        }
    }
    __syncthreads();

    // ---- regression loss + pos count: one anchor per thread (grid > NA_)
    float racc = 0.f, pacc = 0.f;
    {
        unsigned i = blockIdx.x * BLK + threadIdx.x;
        if (i < NA_) {
            int lb = lbin[i];
            if (lb > 0) {
                pacc = 1.f;
                float4 pv = *(const float4*)(pred + (size_t)4 * i);
                float4 gv = *(const float4*)(gt + (size_t)4 * i);
                racc = sl1(pv.x - gv.x) + sl1(pv.y - gv.y)
                     + sl1(pv.z - gv.z) + sl1(pv.w - gv.w);
            }
        }
    }

    // ---- focal sweep: 64 B (16 elements) per lane-iteration, branch-free
    fx2 acc2 = {0.f, 0.f};
    unsigned stride = gridDim.x * BLK;
    for (unsigned i = blockIdx.x * BLK + threadIdx.x; i < NE16; i += stride) {
        fx4 x0 = conf4[4u * i];          // elements 16i..16i+3
        fx4 x1 = conf4[4u * i + 1u];
        fx4 x2 = conf4[4u * i + 2u];
        fx4 x3 = conf4[4u * i + 3u];
        unsigned i16 = i * 16u;
        unsigned a  = i16 / CTOT;        // magic-mul div
        unsigned c0 = i16 - a * CTOT;    // even, 0..276
        // inline rowid from lbin (no precomputed array)
        unsigned bA = a / A_;            // magic-mul div
        unsigned rA = a - bA * A_;
        unsigned bB = bA + ((rA + 1u == A_) ? 1u : 0u);
        int lbA = lbin[a];
        int lbB = lbin[(a + 1u < NA_) ? (a + 1u) : (NA_ - 1u)]; // clamped; dead
                                         // when a is the last anchor (no cross)
        bool okA = lbA >= 0, okB = lbB >= 0;
        unsigned duA = (lbA > 0) ? (unsigned)lbA : 0u;
        unsigned duB = (lbB > 0) ? (unsigned)lbB : 0u;
        unsigned bwA = okA ? (bA * ROWS + duA) * WPR : 0u;
        unsigned bwB = okB ? (bB * ROWS + duB) * WPR : 0u;
        float mA = okA ? 1.f : 0.f;
        float mB = okB ? 1.f : 0.f;
        float c25A = 0.25f * mA, c75A = 0.75f * mA;
        float c25B = 0.25f * mB, c75B = 0.75f * mB;
        unsigned wi = c0 >> 5, sh = c0 & 31u;     // wi <= 8
        unsigned w0  = lbits[bwA + wi];
        unsigned w1  = lbits[bwA + wi + 1u];      // WPR=11 keeps this in-row
        unsigned wB0 = lbits[bwB];
        // 16-bit window of row-A labels at c0 (sh+15 <= 46 < 64: covered)
        unsigned wfull = (unsigned)((((unsigned long long)w1 << 32) | w0) >> sh);
        unsigned bnd  = CTOT - c0;                // elements k < bnd belong to A
        bool cross    = bnd < 16u;                // c0 >= 264; bnd in {2..14}, even
        unsigned w16  = cross ? ((wfull & ((1u << bnd) - 1u)) | (wB0 << bnd))
                              : wfull;
        // bnd even -> pairs never straddle; select coefs per pair
        #define PSEL(k) ((cross && bnd <= (2u*(k))) )
        float q25_1 = PSEL(1) ? c25B : c25A, q75_1 = PSEL(1) ? c75B : c75A;
        float q25_2 = PSEL(2) ? c25B : c25A, q75_2 = PSEL(2) ? c75B : c75A;
        float q25_3 = PSEL(3) ? c25B : c25A, q75_3 = PSEL(3) ? c75B : c75A;
        float q25_4 = PSEL(4) ? c25B : c25A, q75_4 = PSEL(4) ? c75B : c75A;
        float q25_5 = PSEL(5) ? c25B : c25A, q75_5 = PSEL(5) ? c75B : c75A;
        float q25_6 = PSEL(6) ? c25B : c25A, q75_6 = PSEL(6) ? c75B : c75A;
        float q25_7 = PSEL(7) ? c25B : c25A, q75_7 = PSEL(7) ? c75B : c75A;
        #undef PSEL
        acc2 = pair_focal(x0.x, x0.y,  w16 & 3u,        c25A, c75A, acc2);
        acc2 = pair_focal(x0.z, x0.w, (w16 >>  2) & 3u, q25_1, q75_1, acc2);
        acc2 = pair_focal(x1.x, x1.y, (w16 >>  4) & 3u, q25_2, q75_2, acc2);
        acc2 = pair_focal(x1.z, x1.w, (w16 >>  6) & 3u, q25_3, q75_3, acc2);
        acc2 = pair_focal(x2.x, x2.y, (w16 >>  8) & 3u, q25_4, q75_4, acc2);
        acc2 = pair_focal(x2.z, x2.w, (w16 >> 10) & 3u, q25_5, q75_5, acc2);
        acc2 = pair_focal(x3.x, x3.y, (w16 >> 12) & 3u, q25_6, q75_6, acc2);
        acc2 = pair_focal(x3.z, x3.w, (w16 >> 14) & 3u, q25_7, q75_7, acc2);
    }

    __shared__ float sdata[BLK / 64];
    float rc = block_reduce(acc2.x + acc2.y, sdata);
    __syncthreads();
    float rr = block_reduce(racc, sdata);
    __syncthreads();
    float rp = block_reduce(pacc, sdata);
    if (threadIdx.x == 0) {
        cls_part[blockIdx.x] = rc;
        reg_part[blockIdx.x] = rr;
        pos_part[blockIdx.x] = rp;
    }
}

// Deterministic final reduction + normalization (tiny stream-ordered kernel).
__global__ void finalize_kernel(
    const float* __restrict__ cls_part, const float* __restrict__ reg_part,
    const float* __restrict__ pos_part, float* __restrict__ out)
{
    __shared__ float sdata[256 / 64];
    float c = 0.f, r = 0.f, pz = 0.f;
    for (int i = threadIdx.x; i < GRID_CLS; i += blockDim.x) {
        c  += cls_part[i];
        r  += reg_part[i];
        pz += pos_part[i];
    }
    c = block_reduce(c, sdata);
    __syncthreads();
    r = block_reduce(r, sdata);
    __syncthreads();
    pz = block_reduce(pz, sdata);
    if (threadIdx.x == 0) {
        float np = fmaxf(1.f, pz);
        out[0] = r / (np * 4.f);   // regression_loss
        out[1] = c / np;           // cls_loss
    }
}

// ---------------- launch ----------------

extern "C" void kernel_launch(void* const* d_in, const int* in_sizes, int n_in,
                              void* d_out, int out_size, void* d_ws, size_t ws_size,
                              hipStream_t stream) {
    const float* conf = (const float*)d_in[0];
    const float* pred = (const float*)d_in[1];
    const float* gt   = (const float*)d_in[2];
    const int*   gtl  = (const int*)d_in[3];
    const int*   lbin = (const int*)d_in[4];
    float* out = (float*)d_out;

    float* cls_part = (float*)d_ws;
    float* reg_part = cls_part + GRID_CLS;
    float* pos_part = reg_part + GRID_CLS;

    hipLaunchKernelGGL(cls_kernel, dim3(GRID_CLS), dim3(BLK), 0, stream,
                       (const fx4*)conf, lbin, gtl, pred, gt,
                       cls_part, reg_part, pos_part);
    hipLaunchKernelGGL(finalize_kernel, dim3(1), dim3(256), 0, stream,
                       cls_part, reg_part, pos_part, out);
}